// Round 11
// baseline (445.210 us; speedup 1.0000x reference)
//
#include <hip/hip_runtime.h>
#include <hip/hip_bf16.h>

typedef __attribute__((ext_vector_type(8))) short short8;
typedef __attribute__((ext_vector_type(4))) short s16x4;
typedef __attribute__((ext_vector_type(4))) float f32x4;

#define MFMA_BF16(A, B, C) __builtin_amdgcn_mfma_f32_16x16x32_bf16(A, B, C, 0, 0, 0)

// async global->LDS, 16B per lane. LDS dest is wave-uniform base + lane*16.
__device__ __forceinline__ void gload_lds16(const __hip_bfloat16* g, __hip_bfloat16* l) {
  __builtin_amdgcn_global_load_lds(
      (const __attribute__((address_space(1))) unsigned int*)g,
      (__attribute__((address_space(3))) unsigned int*)l, 16, 0, 0);
}

// NaN/Inf tripwire (fast-math-immune): finite -> x, else -> repl.
__device__ __forceinline__ float finite_or(float x, float repl) {
  unsigned u;
  __builtin_memcpy(&u, &x, 4);
  return ((u & 0x7f800000u) == 0x7f800000u) ? repl : x;
}

__device__ __forceinline__ short bf16_bits(float x) {
  __hip_bfloat16 b = __float2bfloat16(x);
  short s;
  __builtin_memcpy(&s, &b, 2);
  return s;
}

__device__ __forceinline__ short8 pack8(f32x4 a, f32x4 b) {
  short8 r;
  r[0] = bf16_bits(a[0]); r[1] = bf16_bits(a[1]);
  r[2] = bf16_bits(a[2]); r[3] = bf16_bits(a[3]);
  r[4] = bf16_bits(b[0]); r[5] = bf16_bits(b[1]);
  r[6] = bf16_bits(b[2]); r[7] = bf16_bits(b[3]);
  return r;
}

// ---------------------------------------------------------------------------
// f32 -> bf16 bulk conversion (unchanged).
// ---------------------------------------------------------------------------
__global__ __launch_bounds__(256) void cvt_kernel(
    const float* x0, const float* x1, const float* x2,
    const float* w0, const float* w1, const float* w2, const float* w3,
    __hip_bfloat16* y0, __hip_bfloat16* y1, __hip_bfloat16* y2,
    __hip_bfloat16* u0, __hip_bfloat16* u1, __hip_bfloat16* u2, __hip_bfloat16* u3)
{
  const int z = blockIdx.y;
  const float* s = z == 0 ? x0 : z == 1 ? x1 : z == 2 ? x2
                 : z == 3 ? w0 : z == 4 ? w1 : z == 5 ? w2 : w3;
  __hip_bfloat16* d = z == 0 ? y0 : z == 1 ? y1 : z == 2 ? y2
                    : z == 3 ? u0 : z == 4 ? u1 : z == 5 ? u2 : u3;
  const size_t n = (z < 3) ? (size_t)8388608 : (size_t)4194304;
  const size_t stride = (size_t)gridDim.x * 256 * 8;
  for (size_t i = ((size_t)blockIdx.x * 256 + threadIdx.x) * 8; i < n; i += stride) {
    f32x4 a = *(const f32x4*)(s + i);
    f32x4 b = *(const f32x4*)(s + i + 4);
    *(short8*)((short*)d + i) = pack8(a, b);
  }
}

// ---------------------------------------------------------------------------
// Pipelined GEMM (T3+T4) — unchanged from R9/R10 (passing, verified).
// ---------------------------------------------------------------------------
#define GBUF 24576

__device__ __forceinline__ void stage_A(const __hip_bfloat16* Ab, __hip_bfloat16* bufA,
                                        int kcol, int t, int wave) {
#pragma unroll
  for (int r = 0; r < 2; ++r) {
    const int ci = r * 512 + t;
    const int row = ci >> 3, c = ci & 7;
    const int sc = c ^ (row & 7);
    gload_lds16(Ab + (size_t)row * 2048 + kcol + sc * 8, bufA + r * 4096 + wave * 512);
  }
}
__device__ __forceinline__ void stage_Br(const __hip_bfloat16* Bb, __hip_bfloat16* bufB,
                                         int kcol, int t, int wave, int r) {
  const int ci = r * 512 + t;
  const int row = ci >> 3, c = ci & 7;
  const int sc = c ^ (row & 7);
  gload_lds16(Bb + (size_t)row * 2048 + kcol + sc * 8, bufB + r * 4096 + wave * 512);
}

template <typename OutT>
__device__ __forceinline__ void gemm8p_body(
    const __hip_bfloat16* __restrict__ A, const __hip_bfloat16* __restrict__ Bt,
    const float* __restrict__ bias, OutT* __restrict__ C,
    float trip, __hip_bfloat16* sm)
{
  constexpr int K = 2048, N = 2048, NT = K / 64;
  const int t = threadIdx.x, wave = t >> 6, lane = t & 63;
  const int ll = lane & 15, lg = lane >> 4;
  const int wmB = (wave >> 2) * 64, wnB = (wave & 3) * 64;
  const int m0 = blockIdx.y * 128, n0 = blockIdx.x * 256;
  const __hip_bfloat16* Ab = A + (size_t)m0 * K;
  const __hip_bfloat16* Bb = Bt + (size_t)n0 * K;

  f32x4 acc[4][4] = {};

  stage_A(Ab, sm, 0, t, wave);
  stage_Br(Bb, sm + 8192, 0, t, wave, 0);
  stage_Br(Bb, sm + 8192, 0, t, wave, 1);
  stage_Br(Bb, sm + 8192, 0, t, wave, 2);
  stage_Br(Bb, sm + 8192, 0, t, wave, 3);
  stage_A(Ab, sm + GBUF, 64, t, wave);
  stage_Br(Bb, sm + GBUF + 8192, 64, t, wave, 0);
  stage_Br(Bb, sm + GBUF + 8192, 64, t, wave, 1);
  stage_Br(Bb, sm + GBUF + 8192, 64, t, wave, 2);
  stage_Br(Bb, sm + GBUF + 8192, 64, t, wave, 3);
  asm volatile("s_waitcnt vmcnt(6)" ::: "memory");
  __builtin_amdgcn_s_barrier();

  for (int i = 0; i < NT; ++i) {
    const __hip_bfloat16* bufA = sm + (i % 3) * GBUF;
    const __hip_bfloat16* bufB = bufA + 8192;
    const bool pf = (i + 2 < NT);
    __hip_bfloat16* pA = sm + ((i + 2) % 3) * GBUF;
    const int pk = (i + 2) * 64;

#pragma unroll
    for (int kk = 0; kk < 2; ++kk) {
      short8 af[4], bf[4];
#pragma unroll
      for (int f = 0; f < 4; ++f) {
        const int ar = wmB + f * 16 + ll;
        af[f] = *(const short8*)&bufA[ar * 64 + (((kk * 4 + lg) ^ (ar & 7)) << 3)];
        const int br = wnB + f * 16 + ll;
        bf[f] = *(const short8*)&bufB[br * 64 + (((kk * 4 + lg) ^ (br & 7)) << 3)];
      }
      if (pf) {
        if (kk == 0) {
          stage_A(Ab, pA, pk, t, wave);
          stage_Br(Bb, pA + 8192, pk, t, wave, 0);
        } else {
          stage_Br(Bb, pA + 8192, pk, t, wave, 1);
          stage_Br(Bb, pA + 8192, pk, t, wave, 2);
          stage_Br(Bb, pA + 8192, pk, t, wave, 3);
        }
      }
      asm volatile("s_waitcnt lgkmcnt(0)" ::: "memory");
      __builtin_amdgcn_sched_barrier(0);
      __builtin_amdgcn_s_setprio(1);
#pragma unroll
      for (int mi = 0; mi < 4; ++mi)
#pragma unroll
        for (int ni = 0; ni < 4; ++ni)
          acc[mi][ni] = MFMA_BF16(af[mi], bf[ni], acc[mi][ni]);
      __builtin_amdgcn_s_setprio(0);
      __builtin_amdgcn_sched_barrier(0);
    }

    const int rem = NT - 1 - i;
    if (rem >= 2) {
      asm volatile("s_waitcnt vmcnt(6)" ::: "memory");
      __builtin_amdgcn_s_barrier();
    } else if (rem == 1) {
      asm volatile("s_waitcnt vmcnt(0)" ::: "memory");
      __builtin_amdgcn_s_barrier();
    }
  }

#pragma unroll
  for (int mi = 0; mi < 4; ++mi)
#pragma unroll
    for (int ni = 0; ni < 4; ++ni) {
      const int col = n0 + wnB + ni * 16 + ll;
      const float bv = bias[col];
#pragma unroll
      for (int j = 0; j < 4; ++j) {
        const int row = m0 + wmB + mi * 16 + lg * 4 + j;
        const float val = finite_or(acc[mi][ni][j] + bv, trip);
        if constexpr (__is_same(OutT, float))
          C[(size_t)row * N + col] = val;
        else
          C[(size_t)row * N + col] = __float2bfloat16(val);
      }
    }
}

__global__ __launch_bounds__(512) void gemm_qkv_kernel(
    const __hip_bfloat16* xq, const __hip_bfloat16* xk, const __hip_bfloat16* xv,
    const __hip_bfloat16* Wq, const __hip_bfloat16* Wk, const __hip_bfloat16* Wv,
    const float* bq, const float* bk, const float* bv,
    __hip_bfloat16* Q, __hip_bfloat16* K, __hip_bfloat16* V)
{
  __shared__ __align__(16) __hip_bfloat16 sm[3 * GBUF];
  const int z = blockIdx.z;
  const __hip_bfloat16* X = z == 0 ? xq : (z == 1 ? xk : xv);
  const __hip_bfloat16* W = z == 0 ? Wq : (z == 1 ? Wk : Wv);
  const float*          B = z == 0 ? bq : (z == 1 ? bk : bv);
  __hip_bfloat16*       O = z == 0 ? Q  : (z == 1 ? K  : V);
  gemm8p_body<__hip_bfloat16>(X, W, B, O, 20000.0f, sm);
}

__global__ __launch_bounds__(512) void gemm_out_kernel(
    const __hip_bfloat16* A, const __hip_bfloat16* W, const float* b, float* C)
{
  __shared__ __align__(16) __hip_bfloat16 sm[3 * GBUF];
  gemm8p_body<float>(A, W, b, C, 50000.0f, sm);
}

// ---------------------------------------------------------------------------
// V[b*S+s][h*128+d] -> Vt[(bh*128+d)*S + s]   (per-head transpose, bf16)
// ---------------------------------------------------------------------------
__global__ __launch_bounds__(256) void transpose_v_kernel(
    const __hip_bfloat16* __restrict__ V, __hip_bfloat16* __restrict__ Vt)
{
  __shared__ __align__(16) __hip_bfloat16 tile[32][33];
  const int bh = blockIdx.z;
  const int b = bh >> 4, h = bh & 15;
  const int s0 = blockIdx.x * 32, d0 = blockIdx.y * 32;
  const int x = threadIdx.x, y = threadIdx.y;
#pragma unroll
  for (int k = 0; k < 32; k += 8)
    tile[y + k][x] = V[(size_t)(b * 2048 + s0 + y + k) * 2048 + h * 128 + d0 + x];
  __syncthreads();
#pragma unroll
  for (int k = 0; k < 32; k += 8)
    Vt[(size_t)(bh * 128 + d0 + y + k) * 2048 + s0 + x] = tile[x][y + k];
}

// ---------------------------------------------------------------------------
// Causal flash attention v3: swapped-operand, 2 q-fragments per wave
// (32 q/wave, 128 q/block), single-buffered K/V, exp2-domain softmax,
// defer-rescale (THR=8), diagonal-only masking, balanced qi map.
// Grid: x = bh (32), y = qt (16); the 2 blocks a CU gets share bh (L2 reuse)
// and their tile counts sum to exactly 36.
// ---------------------------------------------------------------------------
__global__ __launch_bounds__(256) void attn_kernel(
    const __hip_bfloat16* __restrict__ Qb, const __hip_bfloat16* __restrict__ Kb,
    const __hip_bfloat16* __restrict__ Vt, __hip_bfloat16* __restrict__ Ob)
{
  constexpr int S = 2048, D = 2048, HD = 128;
  __shared__ __align__(16) __hip_bfloat16 Ks[64 * 128];   // 16 KiB, chunk ^= row&7
  __shared__ __align__(16) __hip_bfloat16 Vs[128 * 64];   // 16 KiB, chunk ^= d&7
  __shared__ __align__(16) short Ps[4][2][16 * 64];       // 16 KiB, P^T per wave/frag

  const int t = threadIdx.x, wave = t >> 6, lane = t & 63;
  const int lg = lane >> 4, ll = lane & 15;
  const int bh = blockIdx.x;
  const int qt = blockIdx.y;
  const int qi = (qt < 8) ? 2 * qt : 2 * (15 - qt) + 1;  // balanced: pair sums = 36 tiles
  const int b = bh >> 4, h = bh & 15;
  const int q0 = qi * 128;
  const int qrow0 = q0 + wave * 16 + ll;   // frag0 q-row
  const int qrow1 = qrow0 + 64;            // frag1 q-row
  const int e = ll & 7;
  char* const Psw0 = (char*)&Ps[wave][0][0];
  char* const Psw1 = (char*)&Ps[wave][1][0];

  // precomputed swizzle byte-offsets (loop-invariant; (row&7)==ll&7 since 16%8==0)
  int koff[4], pwoff[4], voff[2], proff[2];
#pragma unroll
  for (int kc = 0; kc < 4; ++kc) koff[kc] = (((kc * 4 + lg) ^ e) << 4);
#pragma unroll
  for (int nf = 0; nf < 4; ++nf)
    pwoff[nf] = ((((nf * 2 + (lg >> 1)) ^ e) << 4) + ((lg & 1) << 3));
#pragma unroll
  for (int ks = 0; ks < 2; ++ks) {
    voff[ks]  = (((ks * 4 + lg) ^ e) << 4);
    proff[ks] = (((ks * 4 + lg) ^ e) << 4);
  }

  // Q fragments (B-operand): row=q, elems d = lg*8+e' + kc*32
  short8 qf0[4], qf1[4];
  {
    const __hip_bfloat16* qp0 = Qb + (size_t)(b * S + qrow0) * D + h * HD + lg * 8;
    const __hip_bfloat16* qp1 = Qb + (size_t)(b * S + qrow1) * D + h * HD + lg * 8;
#pragma unroll
    for (int kc = 0; kc < 4; ++kc) {
      qf0[kc] = *(const short8*)(qp0 + kc * 32);
      qf1[kc] = *(const short8*)(qp1 + kc * 32);
    }
  }

  f32x4 o0[8] = {}, o1[8] = {};
  float m0 = -1e30f, l0 = 0.f, m1 = -1e30f, l1 = 0.f;
  constexpr float C2 = 0.12752707979f;  // (1/sqrt(128)) * log2(e)

  const int NT = 2 * qi + 2;
  for (int tk = 0; tk < NT; ++tk) {
    const int kv0 = tk * 64;
    __syncthreads();  // WAR: prior tile's LDS reads complete
#pragma unroll
    for (int r = 0; r < 4; ++r) {  // K tile 64x128, pre-swizzled source
      const int s = r * 256 + t;
      const int row = s >> 4, ch = s & 15;
      const int sc = ch ^ (row & 7);
      gload_lds16(Kb + (size_t)(b * S + kv0 + row) * D + h * HD + sc * 8,
                  Ks + r * 2048 + wave * 512);
    }
#pragma unroll
    for (int r = 0; r < 4; ++r) {  // V^T tile 128x64
      const int s = r * 256 + t;
      const int d = s >> 3, ch = s & 7;
      const int sc = ch ^ (d & 7);
      gload_lds16(Vt + (size_t)(bh * HD + d) * S + kv0 + sc * 8,
                  Vs + r * 2048 + wave * 512);
    }
    __syncthreads();  // RAW: staging visible (drains vmcnt)

    // wave-uniform frag status
    const bool f0live = (kv0 <= q0 + wave * 16 + 15);       // frag0 not fully masked
    const bool mask0  = (kv0 + 63 > q0 + wave * 16);        // frag0 needs causal mask
    const bool mask1  = (kv0 + 63 > q0 + 64 + wave * 16);   // frag1 needs causal mask

    // S^T = K Q^T for both frags; each kf read feeds 2 MFMAs
    f32x4 s0[4] = {}, s1[4] = {};
    const char* Ksb = (const char*)Ks;
#pragma unroll
    for (int nf = 0; nf < 4; ++nf) {
      const int rbase = nf * 4096 + ll * 256;
#pragma unroll
      for (int kc = 0; kc < 4; ++kc) {
        const short8 kf = *(const short8*)(Ksb + rbase + koff[kc]);
        if (f0live) s0[nf] = MFMA_BF16(kf, qf0[kc], s0[nf]);
        s1[nf] = MFMA_BF16(kf, qf1[kc], s1[nf]);
      }
    }

    // ---- softmax frag0 (log2 domain) ----
    if (f0live) {
      float sv[4][4], mx = -1e30f;
      if (mask0) {
#pragma unroll
        for (int nf = 0; nf < 4; ++nf)
#pragma unroll
          for (int j = 0; j < 4; ++j) {
            float s = s0[nf][j] * C2;
            if (kv0 + nf * 16 + lg * 4 + j > qrow0) s = -1e30f;
            sv[nf][j] = s; mx = fmaxf(mx, s);
          }
      } else {
#pragma unroll
        for (int nf = 0; nf < 4; ++nf)
#pragma unroll
          for (int j = 0; j < 4; ++j) {
            const float s = s0[nf][j] * C2;
            sv[nf][j] = s; mx = fmaxf(mx, s);
          }
      }
      mx = fmaxf(mx, __shfl_xor(mx, 16));
      mx = fmaxf(mx, __shfl_xor(mx, 32));
      if (!__all(mx <= m0 + 8.0f)) {  // T13 defer-rescale
        const float mnew = fmaxf(m0, mx);
        const float alpha = exp2f(m0 - mnew);
        m0 = mnew; l0 *= alpha;
#pragma unroll
        for (int df = 0; df < 8; ++df)
#pragma unroll
          for (int j = 0; j < 4; ++j) o0[df][j] *= alpha;
      }
      float rs = 0.f;
#pragma unroll
      for (int nf = 0; nf < 4; ++nf) {
        s16x4 pk;
#pragma unroll
        for (int j = 0; j < 4; ++j) {
          const float p = exp2f(sv[nf][j] - m0);
          rs += p; pk[j] = bf16_bits(p);
        }
        *(s16x4*)(Psw0 + ll * 128 + pwoff[nf]) = pk;
      }
      rs += __shfl_xor(rs, 16);
      rs += __shfl_xor(rs, 32);
      l0 += rs;
    }

    // ---- softmax frag1 ----
    {
      float sv[4][4], mx = -1e30f;
      if (mask1) {
#pragma unroll
        for (int nf = 0; nf < 4; ++nf)
#pragma unroll
          for (int j = 0; j < 4; ++j) {
            float s = s1[nf][j] * C2;
            if (kv0 + nf * 16 + lg * 4 + j > qrow1) s = -1e30f;
            sv[nf][j] = s; mx = fmaxf(mx, s);
          }
      } else {
#pragma unroll
        for (int nf = 0; nf < 4; ++nf)
#pragma unroll
          for (int j = 0; j < 4; ++j) {
            const float s = s1[nf][j] * C2;
            sv[nf][j] = s; mx = fmaxf(mx, s);
          }
      }
      mx = fmaxf(mx, __shfl_xor(mx, 16));
      mx = fmaxf(mx, __shfl_xor(mx, 32));
      if (!__all(mx <= m1 + 8.0f)) {
        const float mnew = fmaxf(m1, mx);
        const float alpha = exp2f(m1 - mnew);
        m1 = mnew; l1 *= alpha;
#pragma unroll
        for (int df = 0; df < 8; ++df)
#pragma unroll
          for (int j = 0; j < 4; ++j) o1[df][j] *= alpha;
      }
      float rs = 0.f;
#pragma unroll
      for (int nf = 0; nf < 4; ++nf) {
        s16x4 pk;
#pragma unroll
        for (int j = 0; j < 4; ++j) {
          const float p = exp2f(sv[nf][j] - m1);
          rs += p; pk[j] = bf16_bits(p);
        }
        *(s16x4*)(Psw1 + ll * 128 + pwoff[nf]) = pk;
      }
      rs += __shfl_xor(rs, 16);
      rs += __shfl_xor(rs, 32);
      l1 += rs;
    }

    // intra-wave P exchange: drain DS queue, pin order (rule #18)
    asm volatile("s_waitcnt lgkmcnt(0)" ::: "memory");
    __builtin_amdgcn_sched_barrier(0);

    // O^T += V^T P^T ; each vf read feeds 2 MFMAs
    const char* Vsb = (const char*)Vs;
#pragma unroll
    for (int ks = 0; ks < 2; ++ks) {
      short8 pf0 = {};
      if (f0live) pf0 = *(const short8*)(Psw0 + ll * 128 + proff[ks]);
      const short8 pf1 = *(const short8*)(Psw1 + ll * 128 + proff[ks]);
#pragma unroll
      for (int df = 0; df < 8; ++df) {
        const short8 vf = *(const short8*)(Vsb + df * 2048 + ll * 128 + voff[ks]);
        if (f0live) o0[df] = MFMA_BF16(vf, pf0, o0[df]);
        o1[df] = MFMA_BF16(vf, pf1, o1[df]);
      }
    }
  }

  // epilogue: O[q][d], d = df*16 + lg*4 + j ; 8B vector stores per frag
  const float inv0 = 1.0f / l0;
  const float inv1 = 1.0f / l1;
#pragma unroll
  for (int df = 0; df < 8; ++df) {
    s16x4 a, c;
#pragma unroll
    for (int j = 0; j < 4; ++j) {
      a[j] = bf16_bits(finite_or(o0[df][j] * inv0, 300.0f));
      c[j] = bf16_bits(finite_or(o1[df][j] * inv1, 300.0f));
    }
    *(s16x4*)(Ob + (size_t)(b * S + qrow0) * D + h * HD + df * 16 + lg * 4) = a;
    *(s16x4*)(Ob + (size_t)(b * S + qrow1) * D + h * HD + df * 16 + lg * 4) = c;
  }
}

// ---------------------------------------------------------------------------
extern "C" void kernel_launch(void* const* d_in, const int* in_sizes, int n_in,
                              void* d_out, int out_size, void* d_ws, size_t ws_size,
                              hipStream_t stream)
{
  const float* q  = (const float*)d_in[0];
  const float* k  = (const float*)d_in[1];
  const float* v  = (const float*)d_in[2];
  const float* Wq = (const float*)d_in[3];
  const float* bq = (const float*)d_in[4];
  const float* Wk = (const float*)d_in[5];
  const float* bk = (const float*)d_in[6];
  const float* Wv = (const float*)d_in[7];
  const float* bv = (const float*)d_in[8];
  const float* Wo = (const float*)d_in[9];
  const float* bo = (const float*)d_in[10];

  char* wsb = (char*)d_ws;
  const size_t MB = 1024 * 1024;
  __hip_bfloat16* Qw  = (__hip_bfloat16*)(wsb + 0 * MB);
  __hip_bfloat16* Kw  = (__hip_bfloat16*)(wsb + 16 * MB);
  __hip_bfloat16* Vw  = (__hip_bfloat16*)(wsb + 32 * MB);
  __hip_bfloat16* xqb = (__hip_bfloat16*)(wsb + 48 * MB);
  __hip_bfloat16* xkb = (__hip_bfloat16*)(wsb + 64 * MB);
  __hip_bfloat16* xvb = (__hip_bfloat16*)(wsb + 80 * MB);
  __hip_bfloat16* Wqb = (__hip_bfloat16*)(wsb + 96 * MB);
  __hip_bfloat16* Wkb = (__hip_bfloat16*)(wsb + 104 * MB);
  __hip_bfloat16* Wvb = (__hip_bfloat16*)(wsb + 112 * MB);
  __hip_bfloat16* Wob = (__hip_bfloat16*)(wsb + 120 * MB);
  __hip_bfloat16* Vtw = xqb;  // xq dead after QKV GEMM
  __hip_bfloat16* Ow  = xkb;  // xk dead after QKV GEMM

  // 0) convert all f32 operands to bf16
  cvt_kernel<<<dim3(1024, 7), 256, 0, stream>>>(
      q, k, v, Wq, Wk, Wv, Wo, xqb, xkb, xvb, Wqb, Wkb, Wvb, Wob);
  // 1) QKV projections (pipelined GEMM)
  gemm_qkv_kernel<<<dim3(8, 32, 3), 512, 0, stream>>>(
      xqb, xkb, xvb, Wqb, Wkb, Wvb, bq, bk, bv, Qw, Kw, Vw);
  // 2) per-head V transpose -> Vt[bh][d][s]
  transpose_v_kernel<<<dim3(64, 4, 32), dim3(32, 8), 0, stream>>>(Vw, Vtw);
  // 3) causal flash attention -> Ow (bf16); grid (bh, qt)
  attn_kernel<<<dim3(32, 16), 256, 0, stream>>>(Qw, Kw, Vtw, Ow);
  // 4) output projection -> d_out (f32)
  gemm_out_kernel<<<dim3(8, 32), 512, 0, stream>>>(
      Ow, Wob, bo, (float*)d_out);
}